// Round 1
// baseline (129.640 us; speedup 1.0000x reference)
//
#include <hip/hip_runtime.h>
#include <math.h>

#define HIDK 4096
#define NHQ 32
#define NKV 8
#define HD 128
#define NROW 16      // B*Q
#define CMAX 4608
#define CLEN 4096
#define NCHUNK 16
#define CHUNK 256
#define SCALE 0.08838834764831845f   // 1/sqrt(128)

__device__ __forceinline__ float4 ld4(const float* p) { return *reinterpret_cast<const float4*>(p); }

// ---------------------------------------------------------------------------
// Kernel A/D: out[bs, o] = sum_k X[bs, k] * W[o, k]   (M=16, K=4096)
// 1 wave per block, 4 output features per wave. Output split into up to 3
// segments (Wq/Wk/Wv) with separate base pointers and row strides.
// ---------------------------------------------------------------------------
__global__ __launch_bounds__(64) void gemm16_kernel(
    const float* __restrict__ X,
    const float* __restrict__ W1, const float* __restrict__ W2, const float* __restrict__ W3,
    int n1, int n2,
    float* __restrict__ o1, int os1,
    float* __restrict__ o2, int os2,
    float* __restrict__ o3, int os3)
{
  const int lane = threadIdx.x;
  const int o = blockIdx.x * 4;

  const float* Wb; float* ob; int os;
  if (o < n1)           { Wb = W1 + (size_t)o * HIDK;            ob = o1 + o;            os = os1; }
  else if (o < n1 + n2) { const int f = o - n1;      Wb = W2 + (size_t)f * HIDK; ob = o2 + f; os = os2; }
  else                  { const int f = o - n1 - n2; Wb = W3 + (size_t)f * HIDK; ob = o3 + f; os = os3; }

  float acc[NROW][4];
  #pragma unroll
  for (int bs = 0; bs < NROW; ++bs)
    #pragma unroll
    for (int r = 0; r < 4; ++r) acc[bs][r] = 0.f;

  for (int i = 0; i < 16; ++i) {
    const int k0 = i * 256 + lane * 4;
    const float4 w0 = ld4(Wb + 0 * HIDK + k0);
    const float4 w1 = ld4(Wb + 1 * HIDK + k0);
    const float4 w2 = ld4(Wb + 2 * HIDK + k0);
    const float4 w3 = ld4(Wb + 3 * HIDK + k0);
    #pragma unroll
    for (int bs = 0; bs < NROW; ++bs) {
      const float4 h = ld4(X + (size_t)bs * HIDK + k0);
      acc[bs][0] += h.x * w0.x + h.y * w0.y + h.z * w0.z + h.w * w0.w;
      acc[bs][1] += h.x * w1.x + h.y * w1.y + h.z * w1.z + h.w * w1.w;
      acc[bs][2] += h.x * w2.x + h.y * w2.y + h.z * w2.z + h.w * w2.w;
      acc[bs][3] += h.x * w3.x + h.y * w3.y + h.z * w3.z + h.w * w3.w;
    }
  }

  // cross-lane reduction (full butterfly; lane 0 writes)
  #pragma unroll
  for (int m = 1; m < 64; m <<= 1)
    #pragma unroll
    for (int bs = 0; bs < NROW; ++bs)
      #pragma unroll
      for (int r = 0; r < 4; ++r)
        acc[bs][r] += __shfl_xor(acc[bs][r], m, 64);

  if (lane == 0) {
    #pragma unroll
    for (int bs = 0; bs < NROW; ++bs)
      #pragma unroll
      for (int r = 0; r < 4; ++r)
        ob[(size_t)bs * os + r] = acc[bs][r];
  }
}

// ---------------------------------------------------------------------------
// Kernel B: attention over cache chunk. grid = 32 (b,kv) * 16 chunks of 256.
// block = 512 threads (8 waves). 16 rows = 4 group-heads * 4 queries.
// ---------------------------------------------------------------------------
__global__ __launch_bounds__(512) void attn_chunk_kernel(
    const float* __restrict__ qraw, const float* __restrict__ Kc, const float* __restrict__ Vc,
    const float* __restrict__ cosp, const float* __restrict__ sinp,
    float* __restrict__ partO, float* __restrict__ partM, float* __restrict__ partL)
{
  __shared__ float qsh[16][128];       // RoPE'd, pre-scaled q rows
  __shared__ float P[CHUNK][20];       // scores -> probabilities (pad 20 for banks/align)

  const int tid  = threadIdx.x;
  const int lane = tid & 63;
  const int w    = tid >> 6;
  const int bkv   = blockIdx.x >> 4;
  const int chunk = blockIdx.x & 15;
  const int b  = bkv >> 3, kv = bkv & 7;
  const int p0 = chunk * CHUNK;

  // ---- prologue: RoPE(q) * SCALE into LDS ----
  for (int e = tid; e < 2048; e += 512) {
    const int r = e >> 7, d = e & 127;
    const int g = r >> 2, s = r & 3;
    const int h = kv * 4 + g;
    const float* qp = qraw + (size_t)(b * 4 + s) * HIDK + h * HD;
    const float c  = cosp[(b * 4 + s) * HD + d];
    const float sn = sinp[(b * 4 + s) * HD + d];
    const float q0 = qp[d], q1 = qp[d ^ 64];
    const float sgn = (d < 64) ? -1.f : 1.f;
    qsh[r][d] = (q0 * c + sgn * q1 * sn) * SCALE;
  }
  __syncthreads();

  // ---- scores: wave (h2, pq): rows h2*8..+7, positions pq*64..+63 ----
  {
    const int h2 = w >> 2, pq = w & 3;
    const int dsub = lane & 15, psub = lane >> 4;
    float4 qa[8], qb[8];
    #pragma unroll
    for (int rr = 0; rr < 8; ++rr) {
      qa[rr] = *(const float4*)&qsh[h2 * 8 + rr][dsub * 8];
      qb[rr] = *(const float4*)&qsh[h2 * 8 + rr][dsub * 8 + 4];
    }
    const float* Kbase = Kc + ((size_t)(b * 8 + kv) * CMAX + p0 + pq * 64) * HD;
    #pragma unroll 2
    for (int i = 0; i < 16; ++i) {
      const int pl = i * 4 + psub;
      const float* kp = Kbase + (size_t)pl * HD + dsub * 8;
      const float4 ka = ld4(kp), kb = ld4(kp + 4);
      float sc[8];
      #pragma unroll
      for (int rr = 0; rr < 8; ++rr) {
        sc[rr] = ka.x * qa[rr].x + ka.y * qa[rr].y + ka.z * qa[rr].z + ka.w * qa[rr].w
               + kb.x * qb[rr].x + kb.y * qb[rr].y + kb.z * qb[rr].z + kb.w * qb[rr].w;
      }
      #pragma unroll
      for (int m = 1; m <= 8; m <<= 1)
        #pragma unroll
        for (int rr = 0; rr < 8; ++rr)
          sc[rr] += __shfl_xor(sc[rr], m, 64);
      if (dsub == 0) {
        const int pch = pq * 64 + pl;
        *(float4*)&P[pch][h2 * 8]     = make_float4(sc[0], sc[1], sc[2], sc[3]);
        *(float4*)&P[pch][h2 * 8 + 4] = make_float4(sc[4], sc[5], sc[6], sc[7]);
      }
    }
  }
  __syncthreads();

  // ---- chunk softmax: wave handles rows w*2, w*2+1 ----
  {
    #pragma unroll
    for (int rr = 0; rr < 2; ++rr) {
      const int r = w * 2 + rr;
      float v[4];
      #pragma unroll
      for (int k = 0; k < 4; ++k) v[k] = P[lane + 64 * k][r];
      float m = fmaxf(fmaxf(v[0], v[1]), fmaxf(v[2], v[3]));
      #pragma unroll
      for (int mm = 1; mm < 64; mm <<= 1) m = fmaxf(m, __shfl_xor(m, mm, 64));
      float l = 0.f;
      #pragma unroll
      for (int k = 0; k < 4; ++k) { v[k] = __expf(v[k] - m); l += v[k]; }
      #pragma unroll
      for (int mm = 1; mm < 64; mm <<= 1) l += __shfl_xor(l, mm, 64);
      #pragma unroll
      for (int k = 0; k < 4; ++k) P[lane + 64 * k][r] = v[k];
      if (lane == 0) {
        const int g = r >> 2, s = r & 3, h = kv * 4 + g;
        const int idx = ((b * NHQ + h) * 4 + s) * NCHUNK + chunk;
        partM[idx] = m;
        partL[idx] = l;
      }
    }
  }
  __syncthreads();

  // ---- PV: wave (h2, dq): rows h2*8..+7, dims dq*32..+31; lane halves over p ----
  {
    const int h2 = w >> 2, dq = w & 3;
    const int dl = lane & 31, ph = lane >> 5;
    float o[8];
    #pragma unroll
    for (int rr = 0; rr < 8; ++rr) o[rr] = 0.f;
    const float* Vbase = Vc + ((size_t)(b * 8 + kv) * CMAX + p0 + ph * 128) * HD + dq * 32 + dl;
    #pragma unroll 4
    for (int p = 0; p < 128; ++p) {
      const float vv = Vbase[(size_t)p * HD];
      const int pch = ph * 128 + p;
      const float4 pa = *(const float4*)&P[pch][h2 * 8];
      const float4 pb = *(const float4*)&P[pch][h2 * 8 + 4];
      o[0] += pa.x * vv; o[1] += pa.y * vv; o[2] += pa.z * vv; o[3] += pa.w * vv;
      o[4] += pb.x * vv; o[5] += pb.y * vv; o[6] += pb.z * vv; o[7] += pb.w * vv;
    }
    #pragma unroll
    for (int rr = 0; rr < 8; ++rr) o[rr] += __shfl_xor(o[rr], 32, 64);
    if (ph == 0) {
      const int d = dq * 32 + dl;
      #pragma unroll
      for (int rr = 0; rr < 8; ++rr) {
        const int r = h2 * 8 + rr;
        const int g = r >> 2, s = r & 3, h = kv * 4 + g;
        const size_t idx = ((size_t)((b * NHQ + h) * 4 + s) * NCHUNK + chunk) * HD + d;
        partO[idx] = o[rr];
      }
    }
  }
}

// ---------------------------------------------------------------------------
// Kernel C: flash-combine 16 chunk partials + the <=4 new causal tokens.
// grid = 512 (b,h,s) blocks of 64 (one wave).
// ---------------------------------------------------------------------------
__global__ __launch_bounds__(64) void combine_kernel(
    const float* __restrict__ qraw, const float* __restrict__ kraw, const float* __restrict__ vraw,
    const float* __restrict__ cosp, const float* __restrict__ sinp,
    const float* __restrict__ partO, const float* __restrict__ partM, const float* __restrict__ partL,
    float* __restrict__ attn)
{
  const int bid = blockIdx.x;             // ((b*32 + h)*4 + s)
  const int s = bid & 3;
  const int h = (bid >> 2) & 31;
  const int b = bid >> 7;
  const int kv = h >> 2;
  const int lane = threadIdx.x;
  const int d0 = lane * 2;

  float mc[NCHUNK], lc[NCHUNK];
  float M = -INFINITY;
  #pragma unroll
  for (int c = 0; c < NCHUNK; ++c) {
    mc[c] = partM[bid * NCHUNK + c];
    lc[c] = partL[bid * NCHUNK + c];
    M = fmaxf(M, mc[c]);
  }

  // RoPE(q)*SCALE for this row, 2 dims per lane
  float qr0, qr1;
  {
    const float* qp = qraw + (size_t)(b * 4 + s) * HIDK + h * HD;
    const float c0 = cosp[(b * 4 + s) * HD + d0],     sn0 = sinp[(b * 4 + s) * HD + d0];
    const float c1 = cosp[(b * 4 + s) * HD + d0 + 1], sn1 = sinp[(b * 4 + s) * HD + d0 + 1];
    const float sg0 = (d0 < 64) ? -1.f : 1.f;
    const float sg1 = ((d0 + 1) < 64) ? -1.f : 1.f;
    qr0 = (qp[d0] * c0 + sg0 * qp[d0 ^ 64] * sn0) * SCALE;
    qr1 = (qp[d0 + 1] * c1 + sg1 * qp[(d0 + 1) ^ 64] * sn1) * SCALE;
  }

  // scores vs the <=4 new tokens (causal: j <= s)
  float sj[4] = {0.f, 0.f, 0.f, 0.f};
  float Mp = M;
  #pragma unroll
  for (int j = 0; j < 4; ++j) {
    if (j <= s) {
      const float* kp = kraw + (size_t)(b * 4 + j) * 1024 + kv * HD;
      const float c0 = cosp[(b * 4 + j) * HD + d0],     sn0 = sinp[(b * 4 + j) * HD + d0];
      const float c1 = cosp[(b * 4 + j) * HD + d0 + 1], sn1 = sinp[(b * 4 + j) * HD + d0 + 1];
      const float sg0 = (d0 < 64) ? -1.f : 1.f;
      const float sg1 = ((d0 + 1) < 64) ? -1.f : 1.f;
      const float kr0 = kp[d0] * c0 + sg0 * kp[d0 ^ 64] * sn0;
      const float kr1 = kp[d0 + 1] * c1 + sg1 * kp[(d0 + 1) ^ 64] * sn1;
      float part = qr0 * kr0 + qr1 * kr1;
      #pragma unroll
      for (int m = 1; m < 64; m <<= 1) part += __shfl_xor(part, m, 64);
      sj[j] = part;
      Mp = fmaxf(Mp, part);
    }
  }

  float ltot = 0.f;
  float O0 = 0.f, O1 = 0.f;
  #pragma unroll
  for (int c = 0; c < NCHUNK; ++c) {
    const float a = __expf(mc[c] - Mp);
    ltot += lc[c] * a;
    const float2 v = *(const float2*)&partO[((size_t)bid * NCHUNK + c) * HD + d0];
    O0 += a * v.x;
    O1 += a * v.y;
  }
  #pragma unroll
  for (int j = 0; j < 4; ++j) {
    if (j <= s) {
      const float e = __expf(sj[j] - Mp);
      ltot += e;
      const float* vp = vraw + (size_t)(b * 4 + j) * 1024 + kv * HD + d0;
      O0 += e * vp[0];
      O1 += e * vp[1];
    }
  }
  const float inv = 1.f / ltot;
  *(float2*)&attn[(size_t)(b * 4 + s) * HIDK + h * HD + d0] = make_float2(O0 * inv, O1 * inv);
}

// ---------------------------------------------------------------------------
extern "C" void kernel_launch(void* const* d_in, const int* in_sizes, int n_in,
                              void* d_out, int out_size, void* d_ws, size_t ws_size,
                              hipStream_t stream)
{
  const float* hid  = (const float*)d_in[0];
  const float* cosp = (const float*)d_in[1];
  const float* sinp = (const float*)d_in[2];
  const float* Kc   = (const float*)d_in[3];
  const float* Vc   = (const float*)d_in[4];
  const float* Wq   = (const float*)d_in[5];
  const float* Wk   = (const float*)d_in[6];
  const float* Wv   = (const float*)d_in[7];
  const float* Wo   = (const float*)d_in[8];
  float* out = (float*)d_out;

  float* ws    = (float*)d_ws;
  float* qraw  = ws;                 // 16*4096        = 65536
  float* kraw  = ws + 65536;         // 16*1024        = 16384
  float* vraw  = ws + 81920;         // 16*1024        = 16384
  float* attn  = ws + 98304;         // 16*4096        = 65536
  float* partO = ws + 163840;        // 512*16*128     = 1048576
  float* partM = ws + 1212416;       // 512*16         = 8192
  float* partL = ws + 1220608;       // 512*16         = 8192   (total 1228800 floats = 4.92 MB)

  // A: QKV projection (raw, un-roped) -> ws
  gemm16_kernel<<<1536, 64, 0, stream>>>(hid, Wq, Wk, Wv, 4096, 1024,
                                         qraw, 4096, kraw, 1024, vraw, 1024);
  // B: attention over the 4096 cached positions, 16 chunks of 256
  attn_chunk_kernel<<<512, 512, 0, stream>>>(qraw, Kc, Vc, cosp, sinp, partO, partM, partL);
  // C: combine partials + new causal tokens -> attn
  combine_kernel<<<512, 64, 0, stream>>>(qraw, kraw, vraw, cosp, sinp, partO, partM, partL, attn);
  // D: output projection -> d_out
  gemm16_kernel<<<1024, 64, 0, stream>>>(attn, Wo, Wo, Wo, 4096, 0,
                                         out, 4096, out, 4096, out, 4096);
}